// Round 6
// baseline (356.757 us; speedup 1.0000x reference)
//
#include <hip/hip_runtime.h>
#include <stdint.h>
#include <stddef.h>

// ---------- types ----------
typedef __attribute__((ext_vector_type(4)))  int   i32x4;    // MFMA i8 operand
typedef __attribute__((ext_vector_type(16))) int   i32x16;   // 32x32 MFMA acc
typedef __attribute__((ext_vector_type(8)))  short bf16x8;
typedef __attribute__((ext_vector_type(4)))  float f32x4;
typedef __attribute__((ext_vector_type(4)))  float f32x4v;
typedef __attribute__((ext_vector_type(4)))  unsigned short u16x4;

__device__ __forceinline__ unsigned short f2bf(float f) {
    union { float f; unsigned u; } v; v.f = f;
    unsigned r = v.u + 0x7FFFu + ((v.u >> 16) & 1u);
    return (unsigned short)(r >> 16);
}

__device__ __forceinline__ void gload_lds16(const void* g, void* l) {
    __builtin_amdgcn_global_load_lds(
        (const __attribute__((address_space(1))) void*)(g),
        (__attribute__((address_space(3))) void*)(l), 16, 0, 0);
}

__device__ __forceinline__ int pack4(float a, float b, float c, float d, float inv) {
    int r0 = ((int)rintf(a * inv)) & 255;
    int r1 = ((int)rintf(b * inv)) & 255;
    int r2 = ((int)rintf(c * inv)) & 255;
    int r3 = ((int)rintf(d * inv)) & 255;
    return r0 | (r1 << 8) | (r2 << 16) | (r3 << 24);
}

// ---------- convert: x fp32 -> int8 per-row dynamic quant (+ sx per row) ----------
__global__ void cvt_x_q8(const float* __restrict__ x, signed char* __restrict__ xq,
                         float* __restrict__ sx, int K) {
    const int row = blockIdx.x;
    const int t   = threadIdx.x;          // 256 threads
    const float* xr = x + (size_t)row * K;
    const int ng = K / 1024;              // f32x4 groups per thread (K=4096 -> 4)

    f32x4v v[8];
    float am = 0.f;
#pragma unroll
    for (int i = 0; i < 8; ++i) {
        if (i < ng) {
            v[i] = __builtin_nontemporal_load(&((const f32x4v*)xr)[i * 256 + t]);
            am = fmaxf(am, fmaxf(fmaxf(fabsf(v[i][0]), fabsf(v[i][1])),
                                 fmaxf(fabsf(v[i][2]), fabsf(v[i][3]))));
        }
    }
#pragma unroll
    for (int m = 32; m >= 1; m >>= 1) am = fmaxf(am, __shfl_xor(am, m, 64));
    __shared__ float red[4];
    const int w = t >> 6;
    if ((t & 63) == 0) red[w] = am;
    __syncthreads();
    am = fmaxf(fmaxf(red[0], red[1]), fmaxf(red[2], red[3]));

    const float inv = (am > 0.f) ? 127.0f / am : 0.f;
    if (t == 0) sx[row] = (am > 0.f) ? am / 127.0f : 0.f;

    int* oq = (int*)(xq + (size_t)row * K);
#pragma unroll
    for (int i = 0; i < 8; ++i)
        if (i < ng) oq[i * 256 + t] = pack4(v[i][0], v[i][1], v[i][2], v[i][3], inv);
}

// ---------- convert: W int32 -> int8 (values already int8-ranged; exact) ----------
__global__ void cvt_w_q8(const int* __restrict__ w, signed char* __restrict__ o, int n4) {
    int i = blockIdx.x * blockDim.x + threadIdx.x;
    int stride = gridDim.x * blockDim.x;
    for (; i < n4; i += stride) {
        i32x4 a = __builtin_nontemporal_load(&((const i32x4*)w)[i]);
        ((int*)o)[i] = (a[0] & 255) | ((a[1] & 255) << 8) | ((a[2] & 255) << 16) | ((a[3] & 255) << 24);
    }
}

// =====================================================================
// 256x256 int8 GEMM v6: 32x32x32 i8 MFMA (+12% ceiling, half the MFMA
// instrs), plain C stores (v5's NT stores broke L2 write-combining:
// WRITE 262->370MB), XCD supertile remap (per-XCD chunk walks (tn, tm)
// column-major so the 2 blocks sharing a B panel are launch-adjacent
// -> 2nd visit L2-hits; FETCH 541 -> ~300 predicted).
// Schedule unchanged from v5 (proven): 2 barriers/K-tile, counted
// vmcnt(4), both-sides XOR swizzle (chunk16 ^= row&7), setprio around
// MFMA clusters, A(t+2) staged after mid-barrier (race-free).
// 32x32 frags: A/B lane l: row/col = l&31, k = (l>>5)*16 + j (16B read
// at chunk (ks<<1)|(l>>5)); C/D: col=l&31, row=(reg&3)+8*(reg>>2)+
// 4*(l>>5) [m74/m101]. Per-16-lane-group LDS conflict = 2-way (free).
// =====================================================================
#define BM8 256
#define BN8 256
#define BKQ 128   // int8 elems per K-tile (=128 B rows)

__global__ __launch_bounds__(512, 2) void gemm8p_i8(
    const signed char* __restrict__ A,   // [M][K] i8
    const signed char* __restrict__ Bw,  // [N][K] i8
    const float* __restrict__ sx,        // [M] per-row x scale
    const float* __restrict__ scale_p,
    const float* __restrict__ bias,
    float* __restrict__ C,
    int M, int N, int K)
{
    __shared__ __align__(16) char smem[131072];

    const int t    = threadIdx.x;
    const int lane = t & 63;
    const int w    = t >> 6;
    const int wm   = w >> 2;     // 0..1 (128-row half)
    const int wn   = w & 3;      // 0..3 (64-col quarter)

    const int ntn = N / BN8;
    const int ntm = M / BM8;
    int nwg = gridDim.x, bid = blockIdx.x;
    int tm, tn;
    if (((nwg & 7) == 0) && (ntm % 8 == 0)) {
        // XCD supertile: XCD x owns tm in [x*tmB, (x+1)*tmB); chunk walks
        // (c%tmB, c/tmB) so same-tn blocks are adjacent -> B L2 reuse.
        const int x = bid & 7, c = bid >> 3;
        const int tmB = ntm >> 3;
        tm = x * tmB + (c % tmB);
        tn = c / tmB;
    } else if ((nwg & 7) == 0) {
        int swz = (bid & 7) * (nwg >> 3) + (bid >> 3);
        tm = swz / ntn; tn = swz % ntn;
    } else {
        tm = bid / ntn; tn = bid % ntn;
    }
    const int row0 = tm * BM8;
    const int col0 = tn * BN8;

    const int Kb = K;                // row stride BYTES (i8)
    const int NT = K / BKQ;

    const int srow = w * 8 + (lane >> 3);
    const int sc2  = ((lane & 7) ^ (lane >> 3)) * 16;
    const int ldsLaneOff = w * 1024 + lane * 16;

    const char* aG = (const char*)A + (size_t)(row0 + srow) * Kb + sc2;
    const char* bG = (const char*)Bw + (size_t)(col0 + srow) * Kb + sc2;

    // 32x32 frag-read geometry
    const int l31  = lane & 31;
    const int hi   = lane >> 5;
    const int swzr = (l31 & 7) << 4;

    i32x16 acc[4][2] = {};           // [mi 32-row][nj 32-col], 128 acc regs
    i32x4 aF[2][4], aS[2][4], bF[4], bS[4];

#define STG(gbase, h, tj, buf, region) do {                                   \
    const char* _g = (gbase) + (size_t)(h) * 128 * Kb + (size_t)(tj) * 128;   \
    char* _l = &smem[(buf) * 65536 + (region) * 16384 + ldsLaneOff];          \
    gload_lds16(_g, _l);                                                      \
    gload_lds16(_g + (size_t)64 * Kb, _l + 8192);                             \
} while (0)

#define RDA(buf, mt, ks) \
    (*(const i32x4*)&smem[(buf) * 65536 + wm * 16384 + ((mt) * 32 + l31) * 128 \
                          + ((((ks) << 5) | (hi << 4)) ^ swzr)])
#define RDB(buf, nj, ks) \
    (*(const i32x4*)&smem[(buf) * 65536 + (2 + (wn >> 1)) * 16384              \
                          + ((wn & 1) * 64 + (nj) * 32 + l31) * 128            \
                          + ((((ks) << 5) | (hi << 4)) ^ swzr)])

#define MFMA_(a, b, c) (c) = __builtin_amdgcn_mfma_i32_32x32x32_i8((a), (b), (c), 0, 0, 0)
#define BAR() __builtin_amdgcn_s_barrier()
#define FENCE() asm volatile("" ::: "memory")
#define VM4() asm volatile("s_waitcnt vmcnt(4)" ::: "memory")
#define VM0() asm volatile("s_waitcnt vmcnt(0)" ::: "memory")
#define VMNONE() do { } while (0)

// One K-tile: P1..P3 | mid BAR | P4 | VM | boundary BAR (v5 hazard audit
// unchanged: B(t+1) regions' last reads are >=1 boundary-BAR old; A(t+2)
// staged only after mid BAR when all reads of bb.A are chip-wide done).
#define TILE_STEP(tt, bb, stB, stA2, VMW) do {                                        \
    /* P1: aF(mi0-1)+bF(nj0); stage B0(t+1); MFMA (mi0-1 x nj0) */                    \
    _Pragma("unroll") for (int mi = 0; mi < 2; ++mi)                                  \
    _Pragma("unroll") for (int ks = 0; ks < 4; ++ks) aF[mi][ks] = RDA(bb, mi, ks);    \
    _Pragma("unroll") for (int ks = 0; ks < 4; ++ks) bF[ks] = RDB(bb, 0, ks);         \
    if (stB) STG(bG, 0, (tt) + 1, (bb) ^ 1, 2);                                       \
    __builtin_amdgcn_s_setprio(1);                                                    \
    _Pragma("unroll") for (int ks = 0; ks < 4; ++ks)                                  \
    _Pragma("unroll") for (int mi = 0; mi < 2; ++mi)                                  \
        MFMA_(aF[mi][ks], bF[ks], acc[mi][0]);                                        \
    __builtin_amdgcn_s_setprio(0);                                                    \
    /* P2: bS(nj1); stage B1(t+1); MFMA (mi0-1 x nj1) */                              \
    _Pragma("unroll") for (int ks = 0; ks < 4; ++ks) bS[ks] = RDB(bb, 1, ks);         \
    if (stB) STG(bG, 1, (tt) + 1, (bb) ^ 1, 3);                                       \
    __builtin_amdgcn_s_setprio(1);                                                    \
    _Pragma("unroll") for (int ks = 0; ks < 4; ++ks)                                  \
    _Pragma("unroll") for (int mi = 0; mi < 2; ++mi)                                  \
        MFMA_(aF[mi][ks], bS[ks], acc[mi][1]);                                        \
    __builtin_amdgcn_s_setprio(0);                                                    \
    /* P3: aS(mi2-3); MFMA (mi2-3 x nj1) */                                           \
    _Pragma("unroll") for (int mi = 0; mi < 2; ++mi)                                  \
    _Pragma("unroll") for (int ks = 0; ks < 4; ++ks) aS[mi][ks] = RDA(bb, 2 + mi, ks);\
    __builtin_amdgcn_s_setprio(1);                                                    \
    _Pragma("unroll") for (int ks = 0; ks < 4; ++ks)                                  \
    _Pragma("unroll") for (int mi = 0; mi < 2; ++mi)                                  \
        MFMA_(aS[mi][ks], bS[ks], acc[2 + mi][1]);                                    \
    __builtin_amdgcn_s_setprio(0);                                                    \
    BAR(); FENCE();                                                                   \
    /* P4: bF re-read; stage A0,A1(t+2); MFMA (mi2-3 x nj0); tile vmcnt */            \
    _Pragma("unroll") for (int ks = 0; ks < 4; ++ks) bF[ks] = RDB(bb, 0, ks);         \
    if (stA2) { STG(aG, 0, (tt) + 2, (bb), 0); STG(aG, 1, (tt) + 2, (bb), 1); }       \
    __builtin_amdgcn_s_setprio(1);                                                    \
    _Pragma("unroll") for (int ks = 0; ks < 4; ++ks)                                  \
    _Pragma("unroll") for (int mi = 0; mi < 2; ++mi)                                  \
        MFMA_(aS[mi][ks], bF[ks], acc[2 + mi][0]);                                    \
    __builtin_amdgcn_s_setprio(0);                                                    \
    VMW();                                                                            \
    BAR(); FENCE();                                                                   \
} while (0)

    // prologue: tile0 {A0,A1,B0,B1} + tile1 {A0,A1}; vmcnt(4) -> tile0 resident
    STG(aG, 0, 0, 0, 0); STG(aG, 1, 0, 0, 1);
    STG(bG, 0, 0, 0, 2); STG(bG, 1, 0, 0, 3);
    STG(aG, 0, 1, 1, 0); STG(aG, 1, 1, 1, 1);
    VM4();
    BAR(); FENCE();

    for (int tt = 0; tt < NT - 2; tt += 2) {
        TILE_STEP(tt,     0, 1, 1, VM4);
        TILE_STEP(tt + 1, 1, 1, 1, VM4);
    }
    TILE_STEP(NT - 2, 0, 1, 0, VM0);
    TILE_STEP(NT - 1, 1, 0, 0, VMNONE);

    // ---- epilogue: y = acc * (sx[row]*s) + bias[col]; plain (cached) stores;
    // each store instr covers 2 full 128B segments (32 consecutive cols x 2 rows).
    const float s = scale_p[0];
    float bvv[2];
#pragma unroll
    for (int nj = 0; nj < 2; ++nj) bvv[nj] = bias[col0 + wn * 64 + nj * 32 + l31];
#pragma unroll
    for (int mi = 0; mi < 4; ++mi) {
        const int rb = row0 + wm * 128 + mi * 32;
        float sxv[16];
#pragma unroll
        for (int j = 0; j < 16; ++j)
            sxv[j] = sx[rb + (j & 3) + 8 * (j >> 2) + 4 * hi] * s;
#pragma unroll
        for (int nj = 0; nj < 2; ++nj) {
            const int col = col0 + wn * 64 + nj * 32 + l31;
#pragma unroll
            for (int j = 0; j < 16; ++j) {
                const int row = rb + (j & 3) + 8 * (j >> 2) + 4 * hi;
                C[(size_t)row * N + col] = (float)acc[mi][nj][j] * sxv[j] + bvv[nj];
            }
        }
    }
#undef STG
#undef RDA
#undef RDB
#undef TILE_STEP
}

// ---------- fallback: fused fp32->bf16-in-staging GEMM (ws too small / odd shape) ----------
#define BM 128
#define BN 128
#define BK 64

__global__ __launch_bounds__(256, 2) void gemm_fused(
    const float* __restrict__ A,
    const int* __restrict__ Bw,
    const float* __restrict__ scale_p,
    const float* __restrict__ bias,
    float* __restrict__ C,
    int M, int N, int K)
{
    __shared__ unsigned short As[BM * BK];
    __shared__ unsigned short Bs[BN * BK];
    const int t = threadIdx.x, lane = t & 63, w = t >> 6;
    const int wm = w >> 1, wn = w & 1;
    int nwg = gridDim.x, bid = blockIdx.x;
    int swz = (nwg % 8 == 0) ? ((bid & 7) * (nwg >> 3) + (bid >> 3)) : bid;
    const int ntn = N / BN;
    const int row0 = (swz / ntn) * BM, col0 = (swz % ntn) * BN;
    f32x4 acc[4][4] = {};
    const int lr = lane & 15, lkbase = (lane >> 4) * 8;

    for (int kt = 0; kt < K; kt += BK) {
#pragma unroll
        for (int i = 0; i < 8; ++i) {
            const int r = i * 16 + (t >> 4), c = (t & 15) * 4;
            f32x4v v = *(const f32x4v*)&A[(size_t)(row0 + r) * K + kt + c];
            u16x4 o; o[0] = f2bf(v[0]); o[1] = f2bf(v[1]); o[2] = f2bf(v[2]); o[3] = f2bf(v[3]);
            *(u16x4*)&As[r * BK + c] = o;
        }
#pragma unroll
        for (int i = 0; i < 8; ++i) {
            const int r = i * 16 + (t >> 4), c = (t & 15) * 4;
            i32x4 v = *(const i32x4*)&Bw[(size_t)(col0 + r) * K + kt + c];
            u16x4 o; o[0] = f2bf((float)v[0]); o[1] = f2bf((float)v[1]);
                     o[2] = f2bf((float)v[2]); o[3] = f2bf((float)v[3]);
            *(u16x4*)&Bs[r * BK + c] = o;
        }
        __syncthreads();
#pragma unroll
        for (int ks = 0; ks < 2; ++ks) {
            bf16x8 af[4], bfr[4];
#pragma unroll
            for (int m = 0; m < 4; ++m) af[m] = *(const bf16x8*)&As[(wm * 64 + m * 16 + lr) * BK + lkbase + ks * 32];
#pragma unroll
            for (int n = 0; n < 4; ++n) bfr[n] = *(const bf16x8*)&Bs[(wn * 64 + n * 16 + lr) * BK + lkbase + ks * 32];
#pragma unroll
            for (int m = 0; m < 4; ++m)
#pragma unroll
                for (int n = 0; n < 4; ++n)
                    acc[m][n] = __builtin_amdgcn_mfma_f32_16x16x32_bf16(af[m], bfr[n], acc[m][n], 0, 0, 0);
        }
        __syncthreads();
    }
    const float s = scale_p[0];
    const int lq4 = (lane >> 4) * 4;
#pragma unroll
    for (int m = 0; m < 4; ++m)
#pragma unroll
        for (int n = 0; n < 4; ++n) {
            const int col = col0 + wn * 64 + n * 16 + lr;
            const float bv = bias[col];
#pragma unroll
            for (int j = 0; j < 4; ++j) {
                const int row = row0 + wm * 64 + m * 16 + lq4 + j;
                C[(size_t)row * N + col] = acc[m][n][j] * s + bv;
            }
        }
}

extern "C" void kernel_launch(void* const* d_in, const int* in_sizes, int n_in,
                              void* d_out, int out_size, void* d_ws, size_t ws_size,
                              hipStream_t stream) {
    const float* x     = (const float*)d_in[0];
    const int*   w8    = (const int*)d_in[1];
    const float* scale = (const float*)d_in[2];
    const float* bias  = (const float*)d_in[3];
    float* out = (float*)d_out;

    const int N = in_sizes[3];                    // 16384
    const int K = (int)((long)in_sizes[1] / N);   // 4096
    const int M = (int)((long)in_sizes[0] / K);   // 4096

    const size_t needA = (size_t)M * K;           // i8
    const size_t needB = (size_t)N * K;           // i8
    const size_t needS = (size_t)M * sizeof(float);
    const int NT = K / BKQ;

    const bool okShape = (M % BM8 == 0) && (N % BN8 == 0) && (K % BKQ == 0) &&
                         (K % 1024 == 0) && (K / 1024 <= 8) &&
                         (NT >= 4) && ((NT & 1) == 0);

    if (okShape && ws_size >= needA + needB + needS) {
        signed char* Aq = (signed char*)d_ws;
        signed char* Bq = Aq + needA;
        float*       sx = (float*)(Bq + needB);
        cvt_x_q8<<<M, 256, 0, stream>>>(x, Aq, sx, K);
        cvt_w_q8<<<4096, 256, 0, stream>>>(w8, Bq, (int)((size_t)N * K / 4));
        const int nblocks = (M / BM8) * (N / BN8);
        gemm8p_i8<<<nblocks, 512, 0, stream>>>(Aq, Bq, sx, scale, bias, out, M, N, K);
    } else {
        const int nblocks = (M / BM) * (N / BN);
        gemm_fused<<<nblocks, 256, 0, stream>>>(x, w8, scale, bias, out, M, N, K);
    }
}

// Round 7
// 316.914 us; speedup vs baseline: 1.1257x; 1.1257x over previous
//
#include <hip/hip_runtime.h>
#include <stdint.h>
#include <stddef.h>

// ---------- types ----------
typedef __attribute__((ext_vector_type(4)))  int   i32x4;    // MFMA i8 operand / acc
typedef __attribute__((ext_vector_type(8)))  short bf16x8;
typedef __attribute__((ext_vector_type(4)))  float f32x4;
typedef __attribute__((ext_vector_type(4)))  float f32x4v;
typedef __attribute__((ext_vector_type(4)))  unsigned short u16x4;

__device__ __forceinline__ unsigned short f2bf(float f) {
    union { float f; unsigned u; } v; v.f = f;
    unsigned r = v.u + 0x7FFFu + ((v.u >> 16) & 1u);
    return (unsigned short)(r >> 16);
}

__device__ __forceinline__ void gload_lds16(const void* g, void* l) {
    __builtin_amdgcn_global_load_lds(
        (const __attribute__((address_space(1))) void*)(g),
        (__attribute__((address_space(3))) void*)(l), 16, 0, 0);
}

__device__ __forceinline__ int pack4(float a, float b, float c, float d, float inv) {
    int r0 = ((int)rintf(a * inv)) & 255;
    int r1 = ((int)rintf(b * inv)) & 255;
    int r2 = ((int)rintf(c * inv)) & 255;
    int r3 = ((int)rintf(d * inv)) & 255;
    return r0 | (r1 << 8) | (r2 << 16) | (r3 << 24);
}

// ---------- convert: x fp32 -> int8 per-row dynamic quant (+ sx per row) ----------
__global__ void cvt_x_q8(const float* __restrict__ x, signed char* __restrict__ xq,
                         float* __restrict__ sx, int K) {
    const int row = blockIdx.x;
    const int t   = threadIdx.x;          // 256 threads
    const float* xr = x + (size_t)row * K;
    const int ng = K / 1024;              // f32x4 groups per thread (K=4096 -> 4)

    f32x4v v[8];
    float am = 0.f;
#pragma unroll
    for (int i = 0; i < 8; ++i) {
        if (i < ng) {
            v[i] = __builtin_nontemporal_load(&((const f32x4v*)xr)[i * 256 + t]);
            am = fmaxf(am, fmaxf(fmaxf(fabsf(v[i][0]), fabsf(v[i][1])),
                                 fmaxf(fabsf(v[i][2]), fabsf(v[i][3]))));
        }
    }
#pragma unroll
    for (int m = 32; m >= 1; m >>= 1) am = fmaxf(am, __shfl_xor(am, m, 64));
    __shared__ float red[4];
    const int w = t >> 6;
    if ((t & 63) == 0) red[w] = am;
    __syncthreads();
    am = fmaxf(fmaxf(red[0], red[1]), fmaxf(red[2], red[3]));

    const float inv = (am > 0.f) ? 127.0f / am : 0.f;
    if (t == 0) sx[row] = (am > 0.f) ? am / 127.0f : 0.f;

    int* oq = (int*)(xq + (size_t)row * K);
#pragma unroll
    for (int i = 0; i < 8; ++i)
        if (i < ng) oq[i * 256 + t] = pack4(v[i][0], v[i][1], v[i][2], v[i][3], inv);
}

// ---------- convert: W int32 -> int8 (values already int8-ranged; exact) ----------
__global__ void cvt_w_q8(const int* __restrict__ w, signed char* __restrict__ o, int n4) {
    int i = blockIdx.x * blockDim.x + threadIdx.x;
    int stride = gridDim.x * blockDim.x;
    for (; i < n4; i += stride) {
        i32x4 a = __builtin_nontemporal_load(&((const i32x4*)w)[i]);
        ((int*)o)[i] = (a[0] & 255) | ((a[1] & 255) << 8) | ((a[2] & 255) << 16) | ((a[3] & 255) << 24);
    }
}

// =====================================================================
// 256x256 int8 GEMM v7 = recombination of A/B-validated components:
//  - 16x16x64 i8 MFMA + v5 frag/read geometry  [0 LDS conflicts, v5]
//  - XCD supertile remap (col-major chunk walk) [FETCH 541->295MB, v6]
//  - plain cached C stores                      [WRITE 262MB, v6]
//  - 2 barriers/K-tile, counted vmcnt(4), both-sides XOR swizzle,
//    setprio around MFMA clusters, A(t+2) after mid-barrier [v5 audit]
// =====================================================================
#define BM8 256
#define BN8 256
#define BKQ 128   // int8 elems per K-tile (=128 B rows)

__global__ __launch_bounds__(512, 2) void gemm8p_i8(
    const signed char* __restrict__ A,   // [M][K] i8
    const signed char* __restrict__ Bw,  // [N][K] i8
    const float* __restrict__ sx,        // [M] per-row x scale
    const float* __restrict__ scale_p,
    const float* __restrict__ bias,
    float* __restrict__ C,
    int M, int N, int K)
{
    __shared__ __align__(16) char smem[131072];

    const int t    = threadIdx.x;
    const int lane = t & 63;
    const int w    = t >> 6;
    const int wm   = w >> 2;     // 0..1 (128-row half)
    const int wn   = w & 3;      // 0..3 (64-col quarter)

    const int ntn = N / BN8;
    const int ntm = M / BM8;
    int nwg = gridDim.x, bid = blockIdx.x;
    int tm, tn;
    if (((nwg & 7) == 0) && (ntm % 8 == 0)) {
        // XCD supertile: XCD x owns tm in [x*tmB,(x+1)*tmB); chunk walks
        // (c%tmB, c/tmB) so same-tn blocks are launch-adjacent -> B L2 reuse.
        const int x = bid & 7, c = bid >> 3;
        const int tmB = ntm >> 3;
        tm = x * tmB + (c % tmB);
        tn = c / tmB;
    } else if ((nwg & 7) == 0) {
        int swz = (bid & 7) * (nwg >> 3) + (bid >> 3);
        tm = swz / ntn; tn = swz % ntn;
    } else {
        tm = bid / ntn; tn = bid % ntn;
    }
    const int row0 = tm * BM8;
    const int col0 = tn * BN8;

    const int Kb = K;                // row stride BYTES (i8)
    const int NT = K / BKQ;

    const int srow = w * 8 + (lane >> 3);
    const int sc2  = ((lane & 7) ^ (lane >> 3)) * 16;
    const int ldsLaneOff = w * 1024 + lane * 16;

    const char* aG = (const char*)A + (size_t)(row0 + srow) * Kb + sc2;
    const char* bG = (const char*)Bw + (size_t)(col0 + srow) * Kb + sc2;

    // 16x16 frag-read geometry (v5, measured conflict-free)
    const int q    = lane >> 4;        // 0..3 k-chunk
    const int lr   = lane & 15;        // row within 16
    const int swzr = (lr & 7) << 4;    // read-side XOR

    i32x4 acc[8][4] = {};
    i32x4 aF[4][2], aS[4][2], bF[2][2], bS[2][2];

#define STG(gbase, h, tj, buf, region) do {                                   \
    const char* _g = (gbase) + (size_t)(h) * 128 * Kb + (size_t)(tj) * 128;   \
    char* _l = &smem[(buf) * 65536 + (region) * 16384 + ldsLaneOff];          \
    gload_lds16(_g, _l);                                                      \
    gload_lds16(_g + (size_t)64 * Kb, _l + 8192);                             \
} while (0)

#define RDA(buf, mi, ks) \
    (*(const i32x4*)&smem[(buf) * 65536 + wm * 16384 + ((mi) * 16 + lr) * 128 \
                          + ((((ks) << 6) | (q << 4)) ^ swzr)])
#define RDB(buf, nj, ks) \
    (*(const i32x4*)&smem[(buf) * 65536 + (2 + (wn >> 1)) * 16384              \
                          + ((wn & 1) * 64 + (nj) * 16 + lr) * 128             \
                          + ((((ks) << 6) | (q << 4)) ^ swzr)])

#define MFMA_(a, b, c) (c) = __builtin_amdgcn_mfma_i32_16x16x64_i8((a), (b), (c), 0, 0, 0)
#define BAR() __builtin_amdgcn_s_barrier()
#define FENCE() asm volatile("" ::: "memory")
#define VM4() asm volatile("s_waitcnt vmcnt(4)" ::: "memory")
#define VM0() asm volatile("s_waitcnt vmcnt(0)" ::: "memory")
#define VMNONE() do { } while (0)

// One K-tile: P1..P3 | mid BAR | P4 | VM | boundary BAR (v5 hazard audit:
// B(t+1) regions' last reads are >=1 boundary-BAR old; A(t+2) staged only
// after mid BAR when all reads of bb.A are chip-wide complete).
#define TILE_STEP(tt, bb, stB, stA2, VMW) do {                                        \
    /* P1: aF+bF reads; stage B0(t+1); MFMA (m0-3 x n0-1) */                          \
    _Pragma("unroll") for (int mi = 0; mi < 4; ++mi) {                                \
        aF[mi][0] = RDA(bb, mi, 0); aF[mi][1] = RDA(bb, mi, 1); }                     \
    _Pragma("unroll") for (int nj = 0; nj < 2; ++nj) {                                \
        bF[nj][0] = RDB(bb, nj, 0); bF[nj][1] = RDB(bb, nj, 1); }                     \
    if (stB) STG(bG, 0, (tt) + 1, (bb) ^ 1, 2);                                       \
    __builtin_amdgcn_s_setprio(1);                                                    \
    _Pragma("unroll") for (int mi = 0; mi < 4; ++mi)                                  \
    _Pragma("unroll") for (int nj = 0; nj < 2; ++nj) {                                \
        MFMA_(aF[mi][0], bF[nj][0], acc[mi][nj]);                                     \
        MFMA_(aF[mi][1], bF[nj][1], acc[mi][nj]); }                                   \
    __builtin_amdgcn_s_setprio(0);                                                    \
    /* P2: bS reads; stage B1(t+1); MFMA (m0-3 x n2-3) */                             \
    _Pragma("unroll") for (int nj = 0; nj < 2; ++nj) {                                \
        bS[nj][0] = RDB(bb, 2 + nj, 0); bS[nj][1] = RDB(bb, 2 + nj, 1); }             \
    if (stB) STG(bG, 1, (tt) + 1, (bb) ^ 1, 3);                                       \
    __builtin_amdgcn_s_setprio(1);                                                    \
    _Pragma("unroll") for (int mi = 0; mi < 4; ++mi)                                  \
    _Pragma("unroll") for (int nj = 0; nj < 2; ++nj) {                                \
        MFMA_(aF[mi][0], bS[nj][0], acc[mi][2 + nj]);                                 \
        MFMA_(aF[mi][1], bS[nj][1], acc[mi][2 + nj]); }                               \
    __builtin_amdgcn_s_setprio(0);                                                    \
    /* P3: aS reads; MFMA (m4-7 x n2-3) */                                            \
    _Pragma("unroll") for (int mi = 0; mi < 4; ++mi) {                                \
        aS[mi][0] = RDA(bb, 4 + mi, 0); aS[mi][1] = RDA(bb, 4 + mi, 1); }             \
    __builtin_amdgcn_s_setprio(1);                                                    \
    _Pragma("unroll") for (int mi = 0; mi < 4; ++mi)                                  \
    _Pragma("unroll") for (int nj = 0; nj < 2; ++nj) {                                \
        MFMA_(aS[mi][0], bS[nj][0], acc[4 + mi][2 + nj]);                             \
        MFMA_(aS[mi][1], bS[nj][1], acc[4 + mi][2 + nj]); }                           \
    __builtin_amdgcn_s_setprio(0);                                                    \
    BAR(); FENCE();   /* mid: all P1-P3 reads of bb.A complete chip-wide */           \
    /* P4: bF re-read; stage A0,A1(t+2) into bb; MFMA (m4-7 x n0-1) */                \
    _Pragma("unroll") for (int nj = 0; nj < 2; ++nj) {                                \
        bF[nj][0] = RDB(bb, nj, 0); bF[nj][1] = RDB(bb, nj, 1); }                     \
    if (stA2) { STG(aG, 0, (tt) + 2, (bb), 0); STG(aG, 1, (tt) + 2, (bb), 1); }       \
    __builtin_amdgcn_s_setprio(1);                                                    \
    _Pragma("unroll") for (int mi = 0; mi < 4; ++mi)                                  \
    _Pragma("unroll") for (int nj = 0; nj < 2; ++nj) {                                \
        MFMA_(aS[mi][0], bF[nj][0], acc[4 + mi][nj]);                                 \
        MFMA_(aS[mi][1], bF[nj][1], acc[4 + mi][nj]); }                               \
    __builtin_amdgcn_s_setprio(0);                                                    \
    VMW();                                                                            \
    BAR(); FENCE();   /* boundary: tile t+1 staging landed for all waves */           \
} while (0)

    // prologue: tile0 {A0,A1,B0,B1} + tile1 {A0,A1}; vmcnt(4) -> tile0 resident
    STG(aG, 0, 0, 0, 0); STG(aG, 1, 0, 0, 1);
    STG(bG, 0, 0, 0, 2); STG(bG, 1, 0, 0, 3);
    STG(aG, 0, 1, 1, 0); STG(aG, 1, 1, 1, 1);
    VM4();
    BAR(); FENCE();

    for (int tt = 0; tt < NT - 2; tt += 2) {
        TILE_STEP(tt,     0, 1, 1, VM4);
        TILE_STEP(tt + 1, 1, 1, 1, VM4);
    }
    TILE_STEP(NT - 2, 0, 1, 0, VM0);
    TILE_STEP(NT - 1, 1, 0, 0, VMNONE);

    // ---- epilogue: y = acc * (sx[row]*s) + bias[col]; plain cached stores ----
    const float s = scale_p[0];
    float bv[4];
#pragma unroll
    for (int nj = 0; nj < 4; ++nj) bv[nj] = bias[col0 + wn * 64 + nj * 16 + lr];
#pragma unroll
    for (int mi = 0; mi < 8; ++mi) {
        const int rbase = row0 + wm * 128 + mi * 16 + q * 4;
        float sxr[4];
#pragma unroll
        for (int j = 0; j < 4; ++j) sxr[j] = sx[rbase + j] * s;
#pragma unroll
        for (int nj = 0; nj < 4; ++nj) {
            const int col = col0 + wn * 64 + nj * 16 + lr;
#pragma unroll
            for (int j = 0; j < 4; ++j)
                C[(size_t)(rbase + j) * N + col] = (float)acc[mi][nj][j] * sxr[j] + bv[nj];
        }
    }
#undef STG
#undef RDA
#undef RDB
#undef TILE_STEP
}

// ---------- fallback: fused fp32->bf16-in-staging GEMM (ws too small / odd shape) ----------
#define BM 128
#define BN 128
#define BK 64

__global__ __launch_bounds__(256, 2) void gemm_fused(
    const float* __restrict__ A,
    const int* __restrict__ Bw,
    const float* __restrict__ scale_p,
    const float* __restrict__ bias,
    float* __restrict__ C,
    int M, int N, int K)
{
    __shared__ unsigned short As[BM * BK];
    __shared__ unsigned short Bs[BN * BK];
    const int t = threadIdx.x, lane = t & 63, w = t >> 6;
    const int wm = w >> 1, wn = w & 1;
    int nwg = gridDim.x, bid = blockIdx.x;
    int swz = (nwg % 8 == 0) ? ((bid & 7) * (nwg >> 3) + (bid >> 3)) : bid;
    const int ntn = N / BN;
    const int row0 = (swz / ntn) * BM, col0 = (swz % ntn) * BN;
    f32x4 acc[4][4] = {};
    const int lr = lane & 15, lkbase = (lane >> 4) * 8;

    for (int kt = 0; kt < K; kt += BK) {
#pragma unroll
        for (int i = 0; i < 8; ++i) {
            const int r = i * 16 + (t >> 4), c = (t & 15) * 4;
            f32x4v v = *(const f32x4v*)&A[(size_t)(row0 + r) * K + kt + c];
            u16x4 o; o[0] = f2bf(v[0]); o[1] = f2bf(v[1]); o[2] = f2bf(v[2]); o[3] = f2bf(v[3]);
            *(u16x4*)&As[r * BK + c] = o;
        }
#pragma unroll
        for (int i = 0; i < 8; ++i) {
            const int r = i * 16 + (t >> 4), c = (t & 15) * 4;
            i32x4 v = *(const i32x4*)&Bw[(size_t)(col0 + r) * K + kt + c];
            u16x4 o; o[0] = f2bf((float)v[0]); o[1] = f2bf((float)v[1]);
                     o[2] = f2bf((float)v[2]); o[3] = f2bf((float)v[3]);
            *(u16x4*)&Bs[r * BK + c] = o;
        }
        __syncthreads();
#pragma unroll
        for (int ks = 0; ks < 2; ++ks) {
            bf16x8 af[4], bfr[4];
#pragma unroll
            for (int m = 0; m < 4; ++m) af[m] = *(const bf16x8*)&As[(wm * 64 + m * 16 + lr) * BK + lkbase + ks * 32];
#pragma unroll
            for (int n = 0; n < 4; ++n) bfr[n] = *(const bf16x8*)&Bs[(wn * 64 + n * 16 + lr) * BK + lkbase + ks * 32];
#pragma unroll
            for (int m = 0; m < 4; ++m)
#pragma unroll
                for (int n = 0; n < 4; ++n)
                    acc[m][n] = __builtin_amdgcn_mfma_f32_16x16x32_bf16(af[m], bfr[n], acc[m][n], 0, 0, 0);
        }
        __syncthreads();
    }
    const float s = scale_p[0];
    const int lq4 = (lane >> 4) * 4;
#pragma unroll
    for (int m = 0; m < 4; ++m)
#pragma unroll
        for (int n = 0; n < 4; ++n) {
            const int col = col0 + wn * 64 + n * 16 + lr;
            const float bv = bias[col];
#pragma unroll
            for (int j = 0; j < 4; ++j) {
                const int row = row0 + wm * 64 + m * 16 + lq4 + j;
                C[(size_t)row * N + col] = acc[m][n][j] * s + bv;
            }
        }
}

extern "C" void kernel_launch(void* const* d_in, const int* in_sizes, int n_in,
                              void* d_out, int out_size, void* d_ws, size_t ws_size,
                              hipStream_t stream) {
    const float* x     = (const float*)d_in[0];
    const int*   w8    = (const int*)d_in[1];
    const float* scale = (const float*)d_in[2];
    const float* bias  = (const float*)d_in[3];
    float* out = (float*)d_out;

    const int N = in_sizes[3];                    // 16384
    const int K = (int)((long)in_sizes[1] / N);   // 4096
    const int M = (int)((long)in_sizes[0] / K);   // 4096

    const size_t needA = (size_t)M * K;           // i8
    const size_t needB = (size_t)N * K;           // i8
    const size_t needS = (size_t)M * sizeof(float);
    const int NT = K / BKQ;

    const bool okShape = (M % BM8 == 0) && (N % BN8 == 0) && (K % BKQ == 0) &&
                         (K % 1024 == 0) && (K / 1024 <= 8) &&
                         (NT >= 4) && ((NT & 1) == 0);

    if (okShape && ws_size >= needA + needB + needS) {
        signed char* Aq = (signed char*)d_ws;
        signed char* Bq = Aq + needA;
        float*       sx = (float*)(Bq + needB);
        cvt_x_q8<<<M, 256, 0, stream>>>(x, Aq, sx, K);
        cvt_w_q8<<<4096, 256, 0, stream>>>(w8, Bq, (int)((size_t)N * K / 4));
        const int nblocks = (M / BM8) * (N / BN8);
        gemm8p_i8<<<nblocks, 512, 0, stream>>>(Aq, Bq, sx, scale, bias, out, M, N, K);
    } else {
        const int nblocks = (M / BM) * (N / BN);
        gemm_fused<<<nblocks, 256, 0, stream>>>(x, w8, scale, bias, out, M, N, K);
    }
}